// Round 1
// baseline (226.493 us; speedup 1.0000x reference)
//
#include <hip/hip_runtime.h>

// TurboQuant MSE: y = FWHT(x*sigma)/32; idx = searchsorted(boundaries, y, left);
// x_hat = sigma * FWHT(centroids[idx]) / 32.  Outputs: [x_hat (N*D f32), indices (N*D, as f32 values)].
//
// One wave (64 lanes) per row of D=1024. Each lane holds 16 contiguous elements.
// FWHT stage order matches the reference exactly (h = 1..512 ascending, low slot = a+b,
// high slot = a-b) so y is bit-identical and indices are exact.

constexpr int D_DIM  = 1024;
constexpr int N_ROWS = 65536;
constexpr int ELEMS  = 16;   // elements per lane
constexpr int WAVES_PER_BLOCK = 4;

__device__ __forceinline__ void fwht_1024(float v[ELEMS], int lane) {
    // Intra-lane stages: global stride h = 1, 2, 4, 8 (within the 16 contiguous elems)
#pragma unroll
    for (int h = 1; h <= 8; h <<= 1) {
#pragma unroll
        for (int i = 0; i < ELEMS; i += 2 * h) {
#pragma unroll
            for (int j = 0; j < h; ++j) {
                float a = v[i + j];
                float b = v[i + j + h];
                v[i + j]     = a + b;
                v[i + j + h] = a - b;
            }
        }
    }
    // Cross-lane stages: global stride h = 16*m, lane-xor mask m = 1..32 (ascending)
#pragma unroll
    for (int m = 1; m <= 32; m <<= 1) {
        const bool upper = (lane & m) != 0;
#pragma unroll
        for (int j = 0; j < ELEMS; ++j) {
            float p = __shfl_xor(v[j], m, 64);
            // lower lane: a+b ; upper lane: a-b where a is the lower lane's value (= p here)
            v[j] = upper ? (p - v[j]) : (v[j] + p);
        }
    }
}

__global__ __launch_bounds__(256) void tq_kernel(
    const float* __restrict__ x,
    const float* __restrict__ sigma,
    const float* __restrict__ centroids,
    const float* __restrict__ boundaries,
    float* __restrict__ out)   // [0, N*D) = x_hat, [N*D, 2*N*D) = indices (as float)
{
    __shared__ float c_lds[16];
    if (threadIdx.x < 16) c_lds[threadIdx.x] = centroids[threadIdx.x];
    __syncthreads();

    const int wave = threadIdx.x >> 6;
    const int lane = threadIdx.x & 63;
    const int row  = blockIdx.x * WAVES_PER_BLOCK + wave;

    // Boundaries -> registers (uniform address, compiler emits scalar loads)
    float bnd[15];
#pragma unroll
    for (int t = 0; t < 15; ++t) bnd[t] = boundaries[t];

    const float* xr = x + (size_t)row * D_DIM + lane * ELEMS;
    const float* sr = sigma + lane * ELEMS;

    float v[ELEMS];
    float sg[ELEMS];
#pragma unroll
    for (int q = 0; q < 4; ++q) {
        float4 xv = *reinterpret_cast<const float4*>(xr + 4 * q);
        float4 sv = *reinterpret_cast<const float4*>(sr + 4 * q);
        sg[4 * q + 0] = sv.x; sg[4 * q + 1] = sv.y;
        sg[4 * q + 2] = sv.z; sg[4 * q + 3] = sv.w;
        v[4 * q + 0] = xv.x * sv.x;
        v[4 * q + 1] = xv.y * sv.y;
        v[4 * q + 2] = xv.z * sv.z;
        v[4 * q + 3] = xv.w * sv.w;
    }

    // Forward transform
    fwht_1024(v, lane);

    // Quantize: y = v/32 (exact, 2^-5); idx = #{bnd[t] < y}; y_hat = centroids[idx]
    float iv[ELEMS];
#pragma unroll
    for (int j = 0; j < ELEMS; ++j) {
        float y = v[j] * 0.03125f;
        int idx = 0;
#pragma unroll
        for (int t = 0; t < 15; ++t) idx += (bnd[t] < y) ? 1 : 0;
        iv[j] = (float)idx;
        v[j]  = c_lds[idx];
    }

    // Inverse transform (same unnormalized FWHT)
    fwht_1024(v, lane);

    // x_hat = sigma * (fwht(y_hat) * 1/32)  (both multiplies exact)
    float* xo = out + (size_t)row * D_DIM + lane * ELEMS;
    float* io = out + (size_t)N_ROWS * D_DIM + (size_t)row * D_DIM + lane * ELEMS;
#pragma unroll
    for (int q = 0; q < 4; ++q) {
        float4 a;
        a.x = v[4 * q + 0] * 0.03125f * sg[4 * q + 0];
        a.y = v[4 * q + 1] * 0.03125f * sg[4 * q + 1];
        a.z = v[4 * q + 2] * 0.03125f * sg[4 * q + 2];
        a.w = v[4 * q + 3] * 0.03125f * sg[4 * q + 3];
        *reinterpret_cast<float4*>(xo + 4 * q) = a;
        float4 b;
        b.x = iv[4 * q + 0];
        b.y = iv[4 * q + 1];
        b.z = iv[4 * q + 2];
        b.w = iv[4 * q + 3];
        *reinterpret_cast<float4*>(io + 4 * q) = b;
    }
}

extern "C" void kernel_launch(void* const* d_in, const int* in_sizes, int n_in,
                              void* d_out, int out_size, void* d_ws, size_t ws_size,
                              hipStream_t stream) {
    const float* x          = (const float*)d_in[0];
    const float* sigma      = (const float*)d_in[1];
    const float* centroids  = (const float*)d_in[2];
    const float* boundaries = (const float*)d_in[3];
    float* out = (float*)d_out;

    dim3 grid(N_ROWS / WAVES_PER_BLOCK);
    dim3 block(256);
    hipLaunchKernelGGL(tq_kernel, grid, block, 0, stream,
                       x, sigma, centroids, boundaries, out);
}